// Round 4
// baseline (121.822 us; speedup 1.0000x reference)
//
#include <hip/hip_runtime.h>

#define NEGC  (-1000000000.0f)
#define NEG2C (-1.4426950408889634e9f)   // NEGC * log2(e)
#define LOG2E 1.4426950408889634f
#define LN2   0.6931471805599453f

constexpr int B_=64, M_=16, L_=128;
constexpr long OFF_FTS=0;
constexpr long OFF_FMS=OFF_FTS+(long)B_*M_*L_;
constexpr long OFF_LA =OFF_FMS+(long)B_*M_*L_;
constexpr long OFF_ELA=OFF_LA+B_;
constexpr long OFF_LB =OFF_ELA+(long)B_*M_*L_;
constexpr long OFF_ELB=OFF_LB+(long)B_*L_;
constexpr long OFF_ENT=OFF_ELB+(long)B_*L_*M_*L_;
constexpr long OFF_EE =OFF_ENT+B_;

constexpr int LDSS=132;   // staging row stride (2-way alias only = free)

// ---- DPP helpers: 16-lane cross-lane on the VALU pipe ----
template<int CTRL>
__device__ __forceinline__ float dppf(float x){
  return __int_as_float(__builtin_amdgcn_update_dpp(0,__float_as_int(x),CTRL,0xF,0xF,true));
}
__device__ __forceinline__ float row_sum16(float x){
  x += dppf<0xB1>(x); x += dppf<0x4E>(x); x += dppf<0x141>(x); x += dppf<0x140>(x);
  return x;
}
__device__ __forceinline__ float row_shr1(float x){ return dppf<0x111>(x); }

__device__ __forceinline__ float fexp2(float x){
#if __has_builtin(__builtin_amdgcn_exp2f)
  return __builtin_amdgcn_exp2f(x);
#else
  return __builtin_exp2f(x);
#endif
}
__device__ __forceinline__ float flog2(float x){
#if __has_builtin(__builtin_amdgcn_logf)
  return __builtin_amdgcn_logf(x);   // v_log_f32 computes log2
#else
  return __builtin_log2f(x);
#endif
}
__device__ __forceinline__ float frcp(float x){
#if __has_builtin(__builtin_amdgcn_rcpf)
  return __builtin_amdgcn_rcpf(x);
#else
  return 1.0f/x;
#endif
}

// blocks 0..15: forward+entropy (4 b each, duplicated scan for ela/ee tiles)
// blocks 16..47: pass-through copies
// blocks 48..1071: backward, block=(b, j≡k mod 16), 8 j's per block
__global__ __launch_bounds__(128) void tok_main(
    const float* __restrict__ fwd_ts, const float* __restrict__ fwd_ms,
    const float* __restrict__ bwd_ts, const float* __restrict__ bwd_ms,
    const int* __restrict__ lengths, float* __restrict__ out)
{
  __shared__ float tile[8*2048];   // 8 full 16x128 tiles, bank-swizzled rows
  __shared__ float lts[16*LDSS];
  const int tid = threadIdx.x;
  const int blk = blockIdx.x;
  const int m = tid & 15;
  const int g = tid >> 4;          // group 0..7

  if (blk >= 48) {
    // ---------------- backward ----------------
    const int bk = blk - 48;
    const int b = bk >> 4;
    const int k = bk & 15;
    const int j = k + (g << 4);

    // stage bwd_ts * log2(e) into LDS
    const float4* gts = (const float4*)(bwd_ts + (long)b*2048);
    #pragma unroll
    for (int it=0; it<4; ++it){
      int t4 = it*128 + tid;               // 0..511
      float4 a = gts[t4];
      int mr = t4 >> 5, l4 = (t4 & 31) << 2;
      float* dt = lts + mr*LDSS + l4;
      dt[0]=a.x*LOG2E; dt[1]=a.y*LOG2E; dt[2]=a.z*LOG2E; dt[3]=a.w*LOG2E;
    }
    __syncthreads();

    const int i = 127 - j;
    const int len = lengths[b];
    const int lenm1 = len - 1;
    const int thr = i + m;                 // em = (l >= thr)
    float w2 = 0.f, stab = 0.f, la2_keep = 0.f;
    const float* rowt = lts + m*LDSS;
    float* trow = tile + (g << 11) + (m << 7);
    const int swadd = m + 8*g;             // bank swizzle: 2-way only

    for (int l0=0; l0<128; l0+=4){
      float4 tsv = *(const float4*)(rowt + l0);
      float ta[4] = {tsv.x, tsv.y, tsv.z, tsv.w};
      #pragma unroll
      for (int kk=0; kk<4; ++kk){
        const int l = l0 + kk;
        const bool em = (l >= thr);
        // closed-form bwd_ms: (m<=l)&&(l<len); mm = em||m==0
        const bool usew = (em || m==0) && (m <= l) && (l < len);
        float cand2 = (em ? ta[kk] : 0.f) + (usew ? w2 : NEG2C);
        float s = fexp2(cand2 - stab);     // stab = previous la2 (group-uniform)
        float tot = row_sum16(s);
        float la2 = stab + flog2(tot);
        trow[(l + swadd) & 127] = em ? cand2*LN2 : NEGC;
        if (l == lenm1) la2_keep = la2;
        float up = row_shr1(w2);
        w2 = (m==0) ? la2 : up;
        stab = la2;
      }
    }
    if (m == 0) out[OFF_LB + (long)b*128 + j] = la2_keep * LN2;
    __syncthreads();

    // flush: each (b,j) tile = 8KB fully sequential; 1KB contiguous per wave-instr
    const int mm = tid >> 3;               // tile row 0..15
    const int lb = (tid & 7) << 4;         // col base
    #pragma unroll
    for (int t=0; t<8; ++t){
      const int jt = k + (t << 4);
      float* dst = out + OFF_ELB + (((long)b*128 + jt) << 11) + (tid << 4);
      const float* src = tile + (t << 11) + (mm << 7);
      const int sw = mm + 8*t;
      #pragma unroll
      for (int c=0; c<4; ++c){
        const int xb = lb + (c << 2) + sw;
        float4 v = make_float4(src[xb & 127], src[(xb+1) & 127],
                               src[(xb+2) & 127], src[(xb+3) & 127]);
        *(float4*)(dst + (c << 2)) = v;
      }
    }

  } else if (blk < 16) {
    // ---------------- forward + entropy (4 b's; groups 0-3 -> ela, 4-7 -> ee) ----------------
    const int bb = blk*4 + (g & 3);
    const bool isE = (g >= 4);
    const int len = lengths[bb];
    const int lenm1 = len - 1;
    const float* fts = fwd_ts + ((long)bb*16 + m)*128;
    float w2=0.f, wh=0.f, stab=0.f, la2_keep=0.f, h_keep=0.f;
    float* trow = tile + (g << 11) + (m << 7);
    const int swadd = m + 8*g;

    for (int j0=0; j0<128; j0+=4){
      float4 tsv = *(const float4*)(fts + j0);
      float ta[4] = {tsv.x,tsv.y,tsv.z,tsv.w};
      #pragma unroll
      for (int kk=0; kk<4; ++kk){
        const int jj = j0 + kk;
        const bool valid = (m <= jj) && (jj < len);   // closed-form fwd_ms
        float cand2 = ta[kk]*LOG2E + (valid ? w2 : NEG2C);
        float d = cand2 - stab;
        float s = fexp2(d);
        float tot = row_sum16(s);
        float l2t = flog2(tot);
        float la2 = stab + l2t;
        float q = s * frcp(tot);
        float contrib = valid ? q * (wh + (l2t - d)*LN2) : 0.f;
        float h = row_sum16(contrib);
        trow[(jj + swadd) & 127] = isE ? contrib : cand2*LN2;
        if (jj == lenm1){ la2_keep = la2; h_keep = h; }
        float upl = row_shr1(w2);
        float uph = row_shr1(wh);
        w2 = (m==0)? la2 : upl;
        wh = (m==0)? h  : uph;
        stab = la2;
      }
    }
    if (m == 0){
      if (!isE) out[OFF_LA + bb] = la2_keep * LN2;
      else      out[OFF_ENT + bb] = h_keep;
    }
    __syncthreads();
    const int mm = tid >> 3;
    const int lb = (tid & 7) << 4;
    #pragma unroll
    for (int t=0; t<8; ++t){
      const int bt = blk*4 + (t & 3);
      const long base = (t < 4 ? OFF_ELA : OFF_EE) + ((long)bt << 11);
      float* dst = out + base + (tid << 4);
      const float* src = tile + (t << 11) + (mm << 7);
      const int sw = mm + 8*t;
      #pragma unroll
      for (int c=0; c<4; ++c){
        const int xb = lb + (c << 2) + sw;
        float4 v = make_float4(src[xb & 127], src[(xb+1) & 127],
                               src[(xb+2) & 127], src[(xb+3) & 127]);
        *(float4*)(dst + (c << 2)) = v;
      }
    }

  } else {
    // ---------------- pass-through copies (blocks 16..47) ----------------
    const int cbk = blk - 16;
    const float4* s0 = (const float4*)fwd_ts;
    const float4* s1 = (const float4*)fwd_ms;
    float4* d = (float4*)out;
    for (int idx = cbk*128 + tid; idx < 65536; idx += 32*128){
      float4 v = (idx < 32768) ? s0[idx] : s1[idx - 32768];
      d[idx] = v;
    }
  }
}

extern "C" void kernel_launch(void* const* d_in, const int* in_sizes, int n_in,
                              void* d_out, int out_size, void* d_ws, size_t ws_size,
                              hipStream_t stream) {
  const float* fts = (const float*)d_in[0];
  const float* fms = (const float*)d_in[1];
  const float* bts = (const float*)d_in[2];
  const float* bms = (const float*)d_in[3];
  const int*   len = (const int*)d_in[4];
  float* out = (float*)d_out;
  hipLaunchKernelGGL(tok_main, dim3(1072), dim3(128), 0, stream,
                     fts, fms, bts, bms, len, out);
}

// Round 5
// 111.923 us; speedup vs baseline: 1.0884x; 1.0884x over previous
//
#include <hip/hip_runtime.h>

#define NEGC  (-1000000000.0f)
#define NEG2C (-1.4426950408889634e9f)   // NEGC * log2(e)
#define LOG2E 1.4426950408889634f
#define LN2   0.6931471805599453f

constexpr int B_=64, M_=16, L_=128;
constexpr long OFF_FTS=0;
constexpr long OFF_FMS=OFF_FTS+(long)B_*M_*L_;
constexpr long OFF_LA =OFF_FMS+(long)B_*M_*L_;
constexpr long OFF_ELA=OFF_LA+B_;
constexpr long OFF_LB =OFF_ELA+(long)B_*M_*L_;
constexpr long OFF_ELB=OFF_LB+(long)B_*L_;
constexpr long OFF_ENT=OFF_ELB+(long)B_*L_*M_*L_;
constexpr long OFF_EE =OFF_ENT+B_;

constexpr int LDSS=132;   // bwd staging row stride (banks: 4p+l, conflict-free)
constexpr int RSTR=33;    // transpose row stride
constexpr int GSTR=536;   // per-group buffer (16*33=528+8): 24g+p+l banks -> 2-way
constexpr int FR=17;      // fwd tile row stride
constexpr int FT=280;     // fwd tile size (16*17+8)
constexpr int FG=560;     // fwd per-group (ela + ee tiles)

// ---- DPP cross-lane (VALU pipe). 8-lane groups: 0xB1/0x4E/0x141 stay in-group.
template<int CTRL>
__device__ __forceinline__ float dppf(float x){
  return __int_as_float(__builtin_amdgcn_update_dpp(0,__float_as_int(x),CTRL,0xF,0xF,true));
}
__device__ __forceinline__ float red8(float x){   // allreduce-sum over 8 lanes
  x += dppf<0xB1>(x);    // xor1 (quad)
  x += dppf<0x4E>(x);    // xor2 (quad)
  x += dppf<0x141>(x);   // half-mirror = xor7 -> completes 8-sum
  return x;
}
__device__ __forceinline__ float fexp2(float x){ return __builtin_exp2f(x); }
__device__ __forceinline__ float flog2(float x){ return __builtin_log2f(x); }
__device__ __forceinline__ float frcp(float x){
#if __has_builtin(__builtin_amdgcn_rcpf)
  return __builtin_amdgcn_rcpf(x);
#else
  return 1.0f/x;
#endif
}

// grid: blk 0..3 = forward+entropy (16 seqs each); blk 4..515 = backward
// (8 j's per wave, 8-lane groups, 2 m's per lane) + folded pass-through copies.
__global__ __launch_bounds__(128) void tok_main(
    const float* __restrict__ fwd_ts, const float* __restrict__ fwd_ms,
    const float* __restrict__ bwd_ts, const float* __restrict__ bwd_ms,
    const int* __restrict__ lengths, float* __restrict__ out)
{
  __shared__ float smem[10688];   // bwd: 2112 staging + 2*4288 transpose; fwd: 16*560
  const int tid  = threadIdx.x;
  const int blk  = blockIdx.x;
  const int lane = tid & 63;
  const int wv   = tid >> 6;        // wave 0/1
  const int p    = lane & 7;        // lane within 8-lane group
  const int gw   = lane >> 3;       // group within wave 0..7

  if (blk >= 4) {
    // ================= backward =================
    const int bk  = blk - 4;        // 0..511
    const int b   = bk >> 3;
    const int jhi = bk & 7;
    const int j   = jhi*16 + wv*8 + gw;

    // folded pass-through copies: fwd_ts -> out[0:], fwd_ms -> out[32768:]
    if (tid < 32) {
      const float4* s0 = (const float4*)fwd_ts;
      const float4* s1 = (const float4*)fwd_ms;
      int idx = bk*32 + tid;        // 0..16383
      float4 v = (idx < 8192) ? s0[idx] : s1[idx - 8192];
      ((float4*)out)[idx] = v;
    }

    // stage bwd_ts[b] * log2(e) into LDS
    float* lts = smem;
    const float4* gts = (const float4*)(bwd_ts + (long)b*2048);
    #pragma unroll
    for (int it=0; it<4; ++it){
      int t4 = it*128 + tid;
      float4 a = gts[t4];
      int mr = t4 >> 5, l4 = (t4 & 31) << 2;
      float* dt = lts + mr*LDSS + l4;
      dt[0]=a.x*LOG2E; dt[1]=a.y*LOG2E; dt[2]=a.z*LOG2E; dt[3]=a.w*LOG2E;
    }
    __syncthreads();

    const int len = lengths[b];
    const int lenm1 = len - 1;
    const int i0 = 127 - j;
    const int thrA = i0 + p;          // m = p
    const int thrB = i0 + p + 8;      // m = p+8
    float wA=0.f, wB=0.f, stab=0.f, la_keep=0.f;
    const float* rtA = lts + p*LDSS;
    const float* rtB = lts + (p+8)*LDSS;
    float* wbase = smem + 2112 + wv*4288;
    float* bufA = wbase + gw*GSTR + p*RSTR;
    float* bufB = bufA + 8*RSTR;
    const int fm = lane >> 3;         // flush row 0..7
    const int fk = (lane & 7) << 2;   // flush col*4 (covers 32 dwords = 128 B)

    float4 a4 = *(const float4*)(rtA);
    float4 b4 = *(const float4*)(rtB);
    for (int l0 = 0; l0 < 128; l0 += 4){
      float4 a4n, b4n;
      if (l0 < 124){ a4n = *(const float4*)(rtA + l0 + 4);
                     b4n = *(const float4*)(rtB + l0 + 4); }
      float tA[4]={a4.x,a4.y,a4.z,a4.w}, tB[4]={b4.x,b4.y,b4.z,b4.w};
      #pragma unroll
      for (int kk=0; kk<4; ++kk){
        const int l = l0 + kk;
        const bool emA = l >= thrA, emB = l >= thrB;
        const bool useA = (emA || p==0) && (p <= l) && (l < len);
        const bool useB = emB && (p+8 <= l) && (l < len);
        float cA = (emA ? tA[kk] : 0.f) + (useA ? wA : NEG2C);
        float cB = (emB ? tB[kk] : 0.f) + (useB ? wB : NEG2C);
        float sA = fexp2(cA - stab), sB = fexp2(cB - stab);
        float tot = red8(sA + sB);
        float la = stab + flog2(tot);
        bufA[l & 31] = emA ? cA*LN2 : NEGC;
        bufB[l & 31] = emB ? cB*LN2 : NEGC;
        if (l == lenm1) la_keep = la;
        float mir = dppf<0x141>(wA);       // wA[7-p]; at p==0 -> wA[7]
        float shA = dppf<0x111>(wA);       // row_shr:1
        float shB = dppf<0x111>(wB);
        wA = (p==0) ? la  : shA;
        wB = (p==0) ? mir : shB;
        stab = la;
      }
      if ((l0 & 31) == 28) {               // chunk complete: flush 32 l's
        const int lb = l0 - 28;
        #pragma unroll
        for (int g2=0; g2<8; ++g2){
          const int j2 = jhi*16 + wv*8 + g2;
          const float* sb = wbase + g2*GSTR;
          float* db = out + OFF_ELB + ((long)(b*128 + j2) << 11) + lb;
          const float* s1p = sb + fm*RSTR + fk;            // rows 0..7
          *(float4*)(db + fm*128 + fk) =
              make_float4(s1p[0], s1p[1], s1p[2], s1p[3]);
          const float* s2p = sb + (fm+8)*RSTR + fk;        // rows 8..15
          *(float4*)(db + (fm+8)*128 + fk) =
              make_float4(s2p[0], s2p[1], s2p[2], s2p[3]);
        }
      }
      a4 = a4n; b4 = b4n;
    }
    if (p == 0) out[OFF_LB + (long)b*128 + j] = la_keep * LN2;

  } else {
    // ================= forward + entropy (blk 0..3, 16 seqs each) =================
    const int b = blk*16 + wv*8 + gw;
    const int len = lengths[b];
    const int lenm1 = len - 1;
    const float* ftA = fwd_ts + ((long)b*16 + p)*128;
    const float* ftB = fwd_ts + ((long)b*16 + p + 8)*128;
    float w2A=0.f, w2B=0.f, whA=0.f, whB=0.f, stab=0.f, la_keep=0.f, h_keep=0.f;
    float* base = smem + (wv*8 + gw)*FG;
    float* eA  = base + p*FR;            // ela tile (row m=p)
    float* eB  = base + (p+8)*FR;
    float* hA  = base + FT + p*FR;       // ee tile
    float* hB  = base + FT + (p+8)*FR;
    const int fm2 = lane >> 2;           // flush row 0..15
    const int fk2 = (lane & 3) << 2;     // flush col*4 (16 dwords)

    float4 a4 = *(const float4*)(ftA);
    float4 b4 = *(const float4*)(ftB);
    for (int j0 = 0; j0 < 128; j0 += 4){
      float4 a4n, b4n;
      if (j0 < 124){ a4n = *(const float4*)(ftA + j0 + 4);
                     b4n = *(const float4*)(ftB + j0 + 4); }
      float tA[4]={a4.x,a4.y,a4.z,a4.w}, tB[4]={b4.x,b4.y,b4.z,b4.w};
      #pragma unroll
      for (int kk=0; kk<4; ++kk){
        const int jj = j0 + kk;
        const bool vA = (p <= jj) && (jj < len);
        const bool vB = (p+8 <= jj) && (jj < len);
        float cA = tA[kk]*LOG2E + (vA ? w2A : NEG2C);
        float cB = tB[kk]*LOG2E + (vB ? w2B : NEG2C);
        float dA = cA - stab, dB = cB - stab;
        float sA = fexp2(dA), sB = fexp2(dB);
        float tot = red8(sA + sB);
        float lg = flog2(tot);
        float la = stab + lg;
        float rt = frcp(tot);
        float coA = vA ? (sA*rt) * (whA + (lg - dA)*LN2) : 0.f;
        float coB = vB ? (sB*rt) * (whB + (lg - dB)*LN2) : 0.f;
        float h = red8(coA + coB);
        eA[jj & 15] = cA*LN2;
        eB[jj & 15] = cB*LN2;
        hA[jj & 15] = coA;
        hB[jj & 15] = coB;
        if (jj == lenm1){ la_keep = la; h_keep = h; }
        float mirW = dppf<0x141>(w2A);
        float mirH = dppf<0x141>(whA);
        float sWA = dppf<0x111>(w2A), sWB = dppf<0x111>(w2B);
        float sHA = dppf<0x111>(whA), sHB = dppf<0x111>(whB);
        w2A = (p==0) ? la   : sWA;
        w2B = (p==0) ? mirW : sWB;
        whA = (p==0) ? h    : sHA;
        whB = (p==0) ? mirH : sHB;
        stab = la;
      }
      if ((j0 & 15) == 12){                // flush 16-j chunk
        const int jb = j0 - 12;
        #pragma unroll
        for (int g2=0; g2<8; ++g2){
          const int b2 = blk*16 + wv*8 + g2;
          const float* sb = smem + (wv*8 + g2)*FG;
          const float* sp = sb + fm2*FR + fk2;
          *(float4*)(out + OFF_ELA + ((long)b2*16 + fm2)*128 + jb + fk2) =
              make_float4(sp[0], sp[1], sp[2], sp[3]);
          const float* sp2 = sb + FT + fm2*FR + fk2;
          *(float4*)(out + OFF_EE + ((long)b2*16 + fm2)*128 + jb + fk2) =
              make_float4(sp2[0], sp2[1], sp2[2], sp2[3]);
        }
      }
      a4 = a4n; b4 = b4n;
    }
    if (p == 0){
      out[OFF_LA + b] = la_keep * LN2;
      out[OFF_ENT + b] = h_keep;
    }
  }
}

extern "C" void kernel_launch(void* const* d_in, const int* in_sizes, int n_in,
                              void* d_out, int out_size, void* d_ws, size_t ws_size,
                              hipStream_t stream) {
  const float* fts = (const float*)d_in[0];
  const float* fms = (const float*)d_in[1];
  const float* bts = (const float*)d_in[2];
  const float* bms = (const float*)d_in[3];
  const int*   len = (const int*)d_in[4];
  float* out = (float*)d_out;
  hipLaunchKernelGGL(tok_main, dim3(516), dim3(128), 0, stream,
                     fts, fms, bts, bms, len, out);
}

// Round 6
// 108.136 us; speedup vs baseline: 1.1266x; 1.0350x over previous
//
#include <hip/hip_runtime.h>

#define NEGC  (-1000000000.0f)
#define NEG2C (-1.4426950408889634e9f)   // NEGC * log2(e)
#define LOG2E 1.4426950408889634f
#define LN2   0.6931471805599453f

constexpr int B_=64, M_=16, L_=128;
constexpr long OFF_FTS=0;
constexpr long OFF_FMS=OFF_FTS+(long)B_*M_*L_;
constexpr long OFF_LA =OFF_FMS+(long)B_*M_*L_;
constexpr long OFF_ELA=OFF_LA+B_;
constexpr long OFF_LB =OFF_ELA+(long)B_*M_*L_;
constexpr long OFF_ELB=OFF_LB+(long)B_*L_;
constexpr long OFF_ENT=OFF_ELB+(long)B_*L_*M_*L_;
constexpr long OFF_EE =OFF_ENT+B_;

constexpr int LDSS=132;   // staging row stride (banks 4m+l -> 2-way = free)
constexpr int RSTR=33;    // transpose tile row stride
constexpr int GSTR=536;   // per-seq tile (16*33+8); 536&31=24 -> 2-way writes
// bwd LDS map: [0,2112) t2 staging; [2112,4224) E=exp(t) staging; [4224,8512) tiles
constexpr int ET_OFF=2112;
constexpr int TL_OFF=4224;
constexpr int WV_T=2144;  // per-wave tile region (4 seqs * 536)
// fwd LDS (R5 layout, proven): 16 groups * 560
constexpr int FR=17, FT=280, FG=560;

template<int CTRL>
__device__ __forceinline__ float dppf(float x){
  return __int_as_float(__builtin_amdgcn_update_dpp(0,__float_as_int(x),CTRL,0xF,0xF,true));
}
__device__ __forceinline__ float red16(float x){  // allreduce-sum, 16-lane row
  x += dppf<0xB1>(x); x += dppf<0x4E>(x); x += dppf<0x141>(x); x += dppf<0x140>(x);
  return x;
}
__device__ __forceinline__ float red8(float x){   // allreduce-sum, 8-lane half-row
  x += dppf<0xB1>(x); x += dppf<0x4E>(x); x += dppf<0x141>(x);
  return x;
}
__device__ __forceinline__ float fexp2(float x){
#if __has_builtin(__builtin_amdgcn_exp2f)
  return __builtin_amdgcn_exp2f(x);
#else
  return __builtin_exp2f(x);
#endif
}
__device__ __forceinline__ float flog2(float x){
#if __has_builtin(__builtin_amdgcn_logf)
  return __builtin_amdgcn_logf(x);
#else
  return __builtin_log2f(x);
#endif
}
__device__ __forceinline__ float frcp(float x){
#if __has_builtin(__builtin_amdgcn_rcpf)
  return __builtin_amdgcn_rcpf(x);
#else
  return 1.0f/x;
#endif
}

// grid: blk 0..3 fwd+entropy; blk 4..1027 backward (8 seqs/block, 16-lane groups)
__global__ __launch_bounds__(128) void tok_main(
    const float* __restrict__ fwd_ts, const float* __restrict__ fwd_ms,
    const float* __restrict__ bwd_ts, const float* __restrict__ bwd_ms,
    const int* __restrict__ lengths, float* __restrict__ out)
{
  __shared__ float smem[8960];
  const int tid  = threadIdx.x;
  const int blk  = blockIdx.x;
  const int lane = tid & 63;
  const int wv   = tid >> 6;       // wave 0/1
  const int m    = lane & 15;      // lane within 16-group
  const int g    = lane >> 4;      // group 0..3

  if (blk >= 4) {
    // ================= backward (linear-domain scan) =================
    const int bk  = blk - 4;       // 0..1023
    const int b   = bk >> 4;
    const int sub = bk & 15;
    const int j   = sub + 16*(wv*4 + g);

    // folded pass-through copies
    if (tid < 16) {
      const float4* s0 = (const float4*)fwd_ts;
      const float4* s1 = (const float4*)fwd_ms;
      int idx = bk*16 + tid;       // 0..16383
      float4 v = (idx < 8192) ? s0[idx] : s1[idx - 8192];
      ((float4*)out)[idx] = v;
    }

    // stage t2 = t*log2e and E = exp2(t2) = e^t
    const float4* gts = (const float4*)(bwd_ts + (long)b*2048);
    #pragma unroll
    for (int it=0; it<4; ++it){
      int t4 = it*128 + tid;
      float4 a = gts[t4];
      int mr = t4 >> 5, l4 = (t4 & 31) << 2;
      float* dt = smem + mr*LDSS + l4;
      float* de = smem + ET_OFF + mr*LDSS + l4;
      float x0=a.x*LOG2E, x1=a.y*LOG2E, x2=a.z*LOG2E, x3=a.w*LOG2E;
      dt[0]=x0; dt[1]=x1; dt[2]=x2; dt[3]=x3;
      de[0]=fexp2(x0); de[1]=fexp2(x1); de[2]=fexp2(x2); de[3]=fexp2(x3);
    }
    __syncthreads();

    const int len = lengths[b];
    const int lenm1 = len - 1;
    const int i0 = 127 - j;
    const int thr  = i0 + m;                  // em = (l >= thr)
    const int thrp = (m==0) ? 0 : thr;        // usew = (l>=thrp) && (l<len)
    float W = 1.0f, ref2 = 0.0f, la2k = 0.0f, totl = 1.0f;
    const float* rowt = smem + m*LDSS;
    const float* rowe = smem + ET_OFF + m*LDSS;
    float* wbase = smem + TL_OFF + wv*WV_T;
    float* buf = wbase + g*GSTR + m*RSTR;
    const int fm = lane >> 3;                 // flush row 0..7
    const int fk = (lane & 7) << 2;           // flush col*4

    for (int l0 = 0; l0 < 128; l0 += 4){
      float4 t4v = *(const float4*)(rowt + l0);
      float4 e4v = *(const float4*)(rowe + l0);
      float ta[4]={t4v.x,t4v.y,t4v.z,t4v.w};
      float ea[4]={e4v.x,e4v.y,e4v.z,e4v.w};
      #pragma unroll
      for (int kk=0; kk<4; ++kk){
        const int l = l0 + kk;
        const bool em = (l >= thr);
        const bool uw = (l >= thrp) && (l < len);
        // on-chain: mul, cndmask, 4x dpp-add, cndmask — no transcendental
        float e  = em ? ea[kk] : 1.0f;
        float x  = W * e;
        float s  = uw ? x : 0.0f;
        float tot = red16(s);
        // off-chain: elb value via log2(W)
        float w2 = ref2 + flog2(fmaxf(W, 1e-38f));
        float c2 = (em ? ta[kk] : 0.0f) + (uw ? w2 : NEG2C);
        buf[l & 31] = em ? c2*LN2 : NEGC;
        if (l == lenm1) la2k = ref2 + flog2(tot);
        float sh = dppf<0x111>(W);            // row_shr:1
        W = (m==0) ? tot : sh;
        totl = tot;
      }
      if ((l0 & 15) == 12){                   // renorm every 16 steps
        float ef = __builtin_floorf(flog2(fmaxf(totl, 1e-30f)));
        W *= fexp2(-ef);
        ref2 += ef;
      }
      if ((l0 & 31) == 28){                   // flush 32-l chunk, full 128B sectors
        const int lb = l0 - 28;
        #pragma unroll
        for (int g2=0; g2<4; ++g2){
          const int j2 = sub + 16*(wv*4 + g2);
          float* db = out + OFF_ELB + ((long)(b*128 + j2) << 11) + lb;
          const float* s1p = wbase + g2*GSTR + fm*RSTR + fk;
          *(float4*)(db + fm*128 + fk) =
              make_float4(s1p[0], s1p[1], s1p[2], s1p[3]);
          const float* s2p = wbase + g2*GSTR + (fm+8)*RSTR + fk;
          *(float4*)(db + (fm+8)*128 + fk) =
              make_float4(s2p[0], s2p[1], s2p[2], s2p[3]);
        }
      }
    }
    if (m == 0) out[OFF_LB + (long)b*128 + j] = la2k * LN2;

  } else {
    // ================= forward + entropy (R5 structure, 16 seqs/block) =================
    const int p  = lane & 7;
    const int gw = lane >> 3;
    const int b = blk*16 + wv*8 + gw;
    const int len = lengths[b];
    const int lenm1 = len - 1;
    const float* ftA = fwd_ts + ((long)b*16 + p)*128;
    const float* ftB = fwd_ts + ((long)b*16 + p + 8)*128;
    float w2A=0.f, w2B=0.f, whA=0.f, whB=0.f, stab=0.f, la_keep=0.f, h_keep=0.f;
    float* base = smem + (wv*8 + gw)*FG;
    float* eA  = base + p*FR;
    float* eB  = base + (p+8)*FR;
    float* hA  = base + FT + p*FR;
    float* hB  = base + FT + (p+8)*FR;
    const int fm2 = lane >> 2;
    const int fk2 = (lane & 3) << 2;

    float4 a4 = *(const float4*)(ftA);
    float4 b4 = *(const float4*)(ftB);
    for (int j0 = 0; j0 < 128; j0 += 4){
      float4 a4n, b4n;
      if (j0 < 124){ a4n = *(const float4*)(ftA + j0 + 4);
                     b4n = *(const float4*)(ftB + j0 + 4); }
      float tA[4]={a4.x,a4.y,a4.z,a4.w}, tB[4]={b4.x,b4.y,b4.z,b4.w};
      #pragma unroll
      for (int kk=0; kk<4; ++kk){
        const int jj = j0 + kk;
        const bool vA = (p <= jj) && (jj < len);
        const bool vB = (p+8 <= jj) && (jj < len);
        float cA = tA[kk]*LOG2E + (vA ? w2A : NEG2C);
        float cB = tB[kk]*LOG2E + (vB ? w2B : NEG2C);
        float dA = cA - stab, dB = cB - stab;
        float sA = fexp2(dA), sB = fexp2(dB);
        float tot = red8(sA + sB);
        float lg = flog2(tot);
        float la = stab + lg;
        float rt = frcp(tot);
        float coA = vA ? (sA*rt) * (whA + (lg - dA)*LN2) : 0.f;
        float coB = vB ? (sB*rt) * (whB + (lg - dB)*LN2) : 0.f;
        float h = red8(coA + coB);
        eA[jj & 15] = cA*LN2;
        eB[jj & 15] = cB*LN2;
        hA[jj & 15] = coA;
        hB[jj & 15] = coB;
        if (jj == lenm1){ la_keep = la; h_keep = h; }
        float mirW = dppf<0x141>(w2A);
        float mirH = dppf<0x141>(whA);
        float sWA = dppf<0x111>(w2A), sWB = dppf<0x111>(w2B);
        float sHA = dppf<0x111>(whA), sHB = dppf<0x111>(whB);
        w2A = (p==0) ? la   : sWA;
        w2B = (p==0) ? mirW : sWB;
        whA = (p==0) ? h    : sHA;
        whB = (p==0) ? mirH : sHB;
        stab = la;
      }
      if ((j0 & 15) == 12){
        const int jb = j0 - 12;
        #pragma unroll
        for (int g2=0; g2<8; ++g2){
          const int b2 = blk*16 + wv*8 + g2;
          const float* sb = smem + (wv*8 + g2)*FG;
          const float* sp = sb + fm2*FR + fk2;
          *(float4*)(out + OFF_ELA + ((long)b2*16 + fm2)*128 + jb + fk2) =
              make_float4(sp[0], sp[1], sp[2], sp[3]);
          const float* sp2 = sb + FT + fm2*FR + fk2;
          *(float4*)(out + OFF_EE + ((long)b2*16 + fm2)*128 + jb + fk2) =
              make_float4(sp2[0], sp2[1], sp2[2], sp2[3]);
        }
      }
      a4 = a4n; b4 = b4n;
    }
    if (p == 0){
      out[OFF_LA + b] = la_keep * LN2;
      out[OFF_ENT + b] = h_keep;
    }
  }
}

extern "C" void kernel_launch(void* const* d_in, const int* in_sizes, int n_in,
                              void* d_out, int out_size, void* d_ws, size_t ws_size,
                              hipStream_t stream) {
  const float* fts = (const float*)d_in[0];
  const float* fms = (const float*)d_in[1];
  const float* bts = (const float*)d_in[2];
  const float* bms = (const float*)d_in[3];
  const int*   len = (const int*)d_in[4];
  float* out = (float*)d_out;
  hipLaunchKernelGGL(tok_main, dim3(1028), dim3(128), 0, stream,
                     fts, fms, bts, bms, len, out);
}